// Round 3
// baseline (229.963 us; speedup 1.0000x reference)
//
#include <hip/hip_runtime.h>
#include <hip/hip_bf16.h>
#include <cstdint>

#define B_ 8
#define C_ 512
#define T_ 1500
#define N_ (B_*T_)      // 12000 tokens
#define NPAD_ 12032     // 94*128
#define V_ 4096
#define K_ 100

typedef unsigned long long u64;
typedef __attribute__((ext_vector_type(8))) short short8;
typedef __attribute__((ext_vector_type(8))) unsigned short u16x8;
typedef __attribute__((ext_vector_type(4))) float f32x4;

__device__ __forceinline__ unsigned short f2bf(float x){
    __hip_bfloat16 h = __float2bfloat16(x);
    return __builtin_bit_cast(unsigned short, h);
}
__device__ __forceinline__ unsigned short f2h(float x){
    return __builtin_bit_cast(unsigned short, (_Float16)x);
}
__device__ __forceinline__ float h2f(unsigned short h){
    return (float)__builtin_bit_cast(_Float16, h);
}

__device__ __forceinline__ void gll16(const unsigned short* g, unsigned short* l){
    __builtin_amdgcn_global_load_lds(
        (const __attribute__((address_space(1))) void*)g,
        (__attribute__((address_space(3))) void*)l, 16, 0, 0);
}

// ---------------- codebook: fp32 -> bf16 + csq (fp32-exact) ----------------
__global__ __launch_bounds__(256) void cbconv_kernel(const float* __restrict__ CB,
                                                     unsigned short* __restrict__ CBh,
                                                     float* __restrict__ csq){
    int wv = threadIdx.x >> 6, lane = threadIdx.x & 63;
    int r = blockIdx.x * 4 + wv;
    const float4* p4 = (const float4*)(CB + (size_t)r * C_);
    ushort4* o4 = (ushort4*)(CBh + (size_t)r * C_);
    float s = 0.f;
    #pragma unroll
    for (int j = 0; j < 2; ++j){
        float4 v = p4[lane + j*64];
        s += v.x*v.x + v.y*v.y + v.z*v.z + v.w*v.w;
        ushort4 h; h.x = f2bf(v.x); h.y = f2bf(v.y); h.z = f2bf(v.z); h.w = f2bf(v.w);
        o4[lane + j*64] = h;
    }
    #pragma unroll
    for (int o = 32; o; o >>= 1) s += __shfl_down(s, o, 64);
    if (lane == 0) csq[r] = s;
}

// ---------------- student: (B,C,T) fp32 -> embT bf16 (N,C) + esq partials ----------------
__global__ __launch_bounds__(256) void transpose_conv_kernel(const float* __restrict__ S,
                                                             unsigned short* __restrict__ embT,
                                                             float* __restrict__ esq){
    __shared__ float tile[32][33];
    __shared__ float psum[8][33];
    int b  = blockIdx.z;
    int c0 = blockIdx.y * 32;
    int t0 = blockIdx.x * 32;
    int tx = threadIdx.x, ty = threadIdx.y; // 32 x 8
    #pragma unroll
    for (int r = 0; r < 4; ++r){
        int c = c0 + ty + r*8;
        int t = t0 + tx;
        tile[ty + r*8][tx] = (t < T_) ? S[((size_t)b*C_ + c)*T_ + t] : 0.f;
    }
    __syncthreads();
    float ps = 0.f;
    #pragma unroll
    for (int r = 0; r < 4; ++r){ float v = tile[ty + r*8][tx]; ps += v * v; }
    psum[ty][tx] = ps;
    #pragma unroll
    for (int r = 0; r < 4; ++r){
        int t = t0 + ty + r*8;
        int c = c0 + tx;
        if (t < T_) embT[((size_t)b*T_ + t)*C_ + c] = f2bf(tile[tx][ty + r*8]);
    }
    __syncthreads();
    if (ty == 0){
        int t = t0 + tx;
        if (t < T_){
            float s2 = 0.f;
            #pragma unroll
            for (int w = 0; w < 8; ++w) s2 += psum[w][tx];
            atomicAdd(&esq[b*T_ + t], s2);
        }
    }
}

// ---------------- bf16 MFMA GEMM -> fp16 dot matrix ----------------
// 128x128 tile, BK=64 (8 K-steps, 2 barriers each -> half the barrier drains of BK=32).
// LDS tiles are XOR-swizzled (both-sides: pre-swizzled GLOBAL source for the linear
// gll16 dest, XOR on the ds_read address) so 128B-stride b128 reads stay bank-balanced.
// XCD-bijective block swizzle: each XCD owns 4 contiguous col-tiles (B-panel fits its L2).
// Epilogue: LDS-bounce transpose for 256B-contiguous row stores (unchanged from r2).
__global__ __launch_bounds__(256) void gemm_dot_kernel(
    const unsigned short* __restrict__ A, const unsigned short* __restrict__ Bm,
    unsigned short* __restrict__ doth, int row_lo, int row_hi)
{
    __shared__ unsigned short smem[128*136];   // 34816 B; staging (32 KB) aliased in front
    unsigned short* As = smem;                 // 128 rows x 64 elem (swizzled)
    unsigned short* Bs = smem + 128*64;        // 128 rows x 64 elem (swizzled)
    int tid = threadIdx.x, lane = tid & 63, wv = tid >> 6;

    // ---- XCD-aware bijective block swizzle (nwg = 94*32 = 3008, %8 == 0) ----
    int nbx = gridDim.x;
    int hw  = blockIdx.x + nbx * blockIdx.y;
    int nwg = nbx * gridDim.y;
    int lg  = hw;
    if ((nwg & 7) == 0){
        int per = nwg >> 3;
        lg = (hw & 7) * per + (hw >> 3);
    }
    int bx = lg % nbx, by = lg / nbx;
    int row0 = row_lo + bx * 128;
    int col0 = by * 128;

    // ---- staging geometry: pass p covers rows p*32 + wv*8 + (lane>>3), 16B per lane ----
    // LDS physical slot (r, pb) holds global byte-col pb ^ ((r&7)<<4); here the source
    // swizzle reduces to a lane-only constant.
    int rb = wv*8 + (lane >> 3);                        // 0..31
    int ke = (((lane & 7) ^ ((lane >> 3) & 7)) << 3);   // element col 0..56, pre-swizzled

    const unsigned short* ApS[4];
    const unsigned short* BpS[4];
    unsigned short* Adst[4];
    unsigned short* Bdst[4];
    #pragma unroll
    for (int p = 0; p < 4; ++p){
        int ra = row0 + p*32 + rb;
        int ca = (ra < N_) ? ra : N_-1;
        ApS[p] = A  + (size_t)ca * C_ + ke;
        BpS[p] = Bm + (size_t)(col0 + p*32 + rb) * C_ + ke;
        Adst[p] = &As[p*2048 + wv*512];   // ushort units: pass p -> 4096B, wave -> 1024B
        Bdst[p] = &Bs[p*2048 + wv*512];
    }

    int wm = (wv >> 1) * 64, wn = (wv & 1) * 64;
    int fr  = lane & 15;
    int fko = (lane >> 4) * 8;        // element base within 32-k slot
    int sx  = (fr & 7) << 3;          // read-side XOR (elements)

    f32x4 acc[4][4];
    #pragma unroll
    for (int i = 0; i < 4; ++i)
        #pragma unroll
        for (int j = 0; j < 4; ++j) acc[i][j] = (f32x4){0.f, 0.f, 0.f, 0.f};

    for (int kt = 0; kt < C_/64; ++kt){
        int k0 = kt * 64;
        #pragma unroll
        for (int p = 0; p < 4; ++p) gll16(ApS[p] + k0, Adst[p]);
        #pragma unroll
        for (int p = 0; p < 4; ++p) gll16(BpS[p] + k0, Bdst[p]);
        __syncthreads();
        #pragma unroll
        for (int ks = 0; ks < 2; ++ks){
            int kc = (ks*32 + fko) ^ sx;
            short8 af[4], bf[4];
            #pragma unroll
            for (int i = 0; i < 4; ++i) af[i] = *(const short8*)&As[(wm + i*16 + fr)*64 + kc];
            #pragma unroll
            for (int j = 0; j < 4; ++j) bf[j] = *(const short8*)&Bs[(wn + j*16 + fr)*64 + kc];
            #pragma unroll
            for (int i = 0; i < 4; ++i)
                #pragma unroll
                for (int j = 0; j < 4; ++j)
                    acc[i][j] = __builtin_amdgcn_mfma_f32_16x16x32_bf16(bf[j], af[i], acc[i][j], 0, 0, 0);
        }
        __syncthreads();
    }
    // loop ends with a barrier: safe to alias smem for the out-tile.

    // ---- stage 1: pack fp16 into LDS out-tile [128][136] ----
    // D layout (operand-swapped): n = row0 + wm + i*16 + (lane&15)
    //                             v = col0 + wn + j*16 + (lane>>4)*4 + reg
    const int LD = 136;
    int en = lane & 15;
    int ev = (lane >> 4) * 4;
    #pragma unroll
    for (int i = 0; i < 4; ++i){
        int r = wm + i*16 + en;
        #pragma unroll
        for (int j = 0; j < 4; ++j){
            ushort4 h;
            h.x = f2h(acc[i][j][0]);
            h.y = f2h(acc[i][j][1]);
            h.z = f2h(acc[i][j][2]);
            h.w = f2h(acc[i][j][3]);
            *(ushort4*)&smem[r*LD + wn + j*16 + ev] = h;
        }
    }
    __syncthreads();

    // ---- stage 2: coalesced stores, 16 lanes cover one row's 256B ----
    int rr = tid >> 4;          // 0..15
    int cc = (tid & 15) * 8;    // element col, 16B per lane
    #pragma unroll
    for (int it = 0; it < 8; ++it){
        int r = it*16 + rr;
        int n = row0 + r;
        if (n < row_hi){
            u16x8 v = *(const u16x8*)&smem[r*LD + cc];
            *(u16x8*)&doth[(size_t)(n - row_lo) * V_ + col0 + cc] = v;
        }
    }
}

// ---------------- selection v4: wave/row, fp16 dot input, no spills ----------------
__global__ __launch_bounds__(256, 2) void select_kernel(const unsigned short* __restrict__ doth,
                                                        const int* __restrict__ codes,
                                                        const float* __restrict__ esq,
                                                        const float* __restrict__ csq,
                                                        float2* __restrict__ pairbuf,
                                                        int row_lo, int nrows){
    int tid = threadIdx.x, lane = tid & 63, wv = tid >> 6;
    int lrow = blockIdx.x * 4 + wv;
    if (lrow >= nrows) return;               // wave-uniform, no barriers below
    int n = row_lo + lrow;
    const u16x8* r8 = (const u16x8*)(doth + (size_t)lrow * V_);

    __shared__ unsigned hist[4][256] __attribute__((aligned(16)));
    __shared__ unsigned coll[4][64];
    __shared__ unsigned collcnt[4];

    float esq_n = esq[n];
    int code = codes[n];
    float dotc = h2f(doth[(size_t)lrow * V_ + code]);
    unsigned ucode = __float_as_uint(fmaxf(esq_n + csq[code] - 2.f * dotc, 0.f));

    // ---- load + reconstruct d2 bits: u[64] is the only big live array ----
    unsigned u[64];
    #pragma unroll
    for (int j = 0; j < 8; ++j){
        u16x8 h = r8[lane + j*64];
        const float4* cp = (const float4*)(csq + 8*lane + 512*j);
        float4 c0 = cp[0], c1 = cp[1];
        float cs[8] = {c0.x, c0.y, c0.z, c0.w, c1.x, c1.y, c1.z, c1.w};
        #pragma unroll
        for (int e = 0; e < 8; ++e){
            float d2 = fmaxf(esq_n + cs[e] - 2.f * h2f(h[e]), 0.f);
            u[8*j+e] = __float_as_uint(d2);
        }
    }

    // ---- min/max (uint order == float order, all >= 0) ----
    unsigned umin = u[0], umax = u[0];
    #pragma unroll
    for (int k = 1; k < 64; ++k){
        umin = (u[k] < umin) ? u[k] : umin;
        umax = (u[k] > umax) ? u[k] : umax;
    }
    #pragma unroll
    for (int o = 32; o; o >>= 1){
        unsigned a = (unsigned)__shfl_xor((int)umin, o, 64); if (a < umin) umin = a;
        unsigned b = (unsigned)__shfl_xor((int)umax, o, 64); if (b > umax) umax = b;
    }
    // ---- argmin (lowest index among value==umin); v = 8*lane + 512*(k>>3) + (k&7) ----
    unsigned im = 0xFFFFFFFFu;
    #pragma unroll
    for (int k = 0; k < 64; ++k){
        unsigned idx = 8u*(unsigned)lane + (unsigned)(512*(k >> 3) + (k & 7));
        if (u[k] == umin && idx < im) im = idx;
    }
    #pragma unroll
    for (int o = 32; o; o >>= 1){
        unsigned a = (unsigned)__shfl_xor((int)im, o, 64); if (a < im) im = a;
    }
    int idx0 = (int)im;
    float d0 = sqrtf(__uint_as_float(umin));

    // ---- rank-99 threshold t via per-wave histogram + in-bin bitwise search ----
    unsigned t;
    if (umin == umax){
        t = umin;
    } else {
        ((uint4*)&hist[wv][0])[lane] = (uint4){0u,0u,0u,0u};
        if (lane == 0) collcnt[wv] = 0u;
        asm volatile("s_waitcnt lgkmcnt(0)" ::: "memory");
        float fmn = __uint_as_float(umin), fmx = __uint_as_float(umax);
        float invw = 256.0f / (fmx - fmn);
        #pragma unroll
        for (int k = 0; k < 64; ++k){
            float fk = __uint_as_float(u[k]);
            int b = (int)((fk - fmn) * invw); b = (b > 255) ? 255 : b;
            atomicAdd(&hist[wv][b], 1u);
        }
        asm volatile("s_waitcnt lgkmcnt(0)" ::: "memory");
        uint4 hq = ((uint4*)&hist[wv][0])[lane];
        unsigned lsum = hq.x + hq.y + hq.z + hq.w;
        unsigned inc = lsum;
        #pragma unroll
        for (int o = 1; o < 64; o <<= 1){
            unsigned y = (unsigned)__shfl_up((int)inc, o, 64);
            if (lane >= o) inc += y;
        }
        unsigned e0 = inc - lsum;
        unsigned e1 = e0 + hq.x, e2 = e1 + hq.y, e3 = e2 + hq.z, e4 = e3 + hq.w;
        int sel = -1;
        if      (e0 <= 99u && 99u < e1) sel = 0;
        else if (e1 <= 99u && 99u < e2) sel = 1;
        else if (e2 <= 99u && 99u < e3) sel = 2;
        else if (e3 <= 99u && 99u < e4) sel = 3;
        u64 bal = __ballot(sel >= 0);
        int src = __ffsll(bal) - 1;
        unsigned myBk = (unsigned)(4*lane + (sel < 0 ? 0 : sel));
        unsigned myBase = (sel == 1) ? e1 : (sel == 2) ? e2 : (sel == 3) ? e3 : e0;
        int Bk   = __shfl((int)myBk,   src, 64);
        int base = __shfl((int)myBase, src, 64);
        int rk = 99 - base;
        #pragma unroll
        for (int k = 0; k < 64; ++k){
            float fk = __uint_as_float(u[k]);
            int b = (int)((fk - fmn) * invw); b = (b > 255) ? 255 : b;
            if (b == Bk){
                unsigned pos = atomicAdd(&collcnt[wv], 1u);
                if (pos < 64u) coll[wv][pos] = u[k];
            }
        }
        asm volatile("s_waitcnt lgkmcnt(0)" ::: "memory");
        unsigned bcnt = collcnt[wv];
        if (bcnt <= 64u){
            unsigned w = (lane < (int)bcnt) ? coll[wv][lane] : 0xFFFFFFFFu;
            unsigned wmn = (lane < (int)bcnt) ? w : 0xFFFFFFFFu;
            unsigned wmx = (lane < (int)bcnt) ? w : 0u;
            #pragma unroll
            for (int o = 32; o; o >>= 1){
                unsigned a = (unsigned)__shfl_xor((int)wmn, o, 64); if (a < wmn) wmn = a;
                unsigned b = (unsigned)__shfl_xor((int)wmx, o, 64); if (b > wmx) wmx = b;
            }
            unsigned P;
            if (wmn == wmx) P = wmn;
            else {
                int hb = 31 - __clz((int)(wmn ^ wmx));
                unsigned mask = (hb == 31) ? 0xFFFFFFFFu : ((1u << (hb+1)) - 1u);
                P = wmn & ~mask;
                for (int b = hb; b >= 0; --b){
                    unsigned cand = P | (1u << b);
                    int c = __popcll(__ballot(w < cand));
                    if (c <= rk) P = cand;
                }
            }
            t = P;
        } else {
            int hb = 31 - __clz((int)(umin ^ umax));
            unsigned mask = (hb == 31) ? 0xFFFFFFFFu : ((1u << (hb+1)) - 1u);
            unsigned P = umin & ~mask;
            for (int b = hb; b >= 0; --b){
                unsigned cand = P | (1u << b);
                int c = 0;
                #pragma unroll
                for (int k = 0; k < 64; ++k) c += (u[k] < cand) ? 1 : 0;
                #pragma unroll
                for (int o = 32; o; o >>= 1) c += __shfl_xor(c, o, 64);
                if (c <= 99) P = cand;
            }
            t = P;
        }
    }
    float tval = sqrtf(__uint_as_float(t));

    // ---- softmax denom over top-100 (tie multiplicity at t) ----
    float s = 0.f; int cl = 0;
    #pragma unroll
    for (int k = 0; k < 64; ++k){
        if (u[k] < t){ s += __expf(d0 - sqrtf(__uint_as_float(u[k]))); cl++; }
    }
    #pragma unroll
    for (int o = 32; o; o >>= 1){
        s += __shfl_xor(s, o, 64);
        cl += __shfl_xor(cl, o, 64);
    }
    if (lane == 0){
        float S = s + (float)(K_ - cl) * __expf(d0 - tval);
        float dcode = sqrtf(__uint_as_float(ucode));
        if (ucode > t) S += __expf(d0 - dcode) - __expf(d0 - tval);  // include_correct swap
        float nll = dcode - d0 + __logf(S);
        pairbuf[n] = make_float2(nll, (idx0 == code) ? 1.f : 0.f);
    }
}

__global__ __launch_bounds__(1024) void finalize_kernel(const float2* __restrict__ pair,
                                                        float* __restrict__ out){
    int tid = threadIdx.x;
    float sn = 0.f, sh = 0.f;
    for (int i = tid; i < N_; i += 1024){
        float2 p = pair[i]; sn += p.x; sh += p.y;
    }
    #pragma unroll
    for (int o = 32; o; o >>= 1){ sn += __shfl_down(sn, o, 64); sh += __shfl_down(sh, o, 64); }
    __shared__ float a[16], b[16];
    int wv = tid >> 6, lane = tid & 63;
    if (lane == 0){ a[wv] = sn; b[wv] = sh; }
    __syncthreads();
    if (tid == 0){
        float L = 0.f, H = 0.f;
        #pragma unroll
        for (int i = 0; i < 16; ++i){ L += a[i]; H += b[i]; }
        out[0] = L / (float)N_;
        out[1] = H / (float)N_;   // local prediction is always candidate 0
        out[2] = H / (float)N_;
        out[3] = 1.0f;            // include_correct guarantees membership
    }
}

// ---------------- launcher ----------------
extern "C" void kernel_launch(void* const* d_in, const int* in_sizes, int n_in,
                              void* d_out, int out_size, void* d_ws, size_t ws_size,
                              hipStream_t stream){
    const float* S   = (const float*)d_in[0];
    const int* codes = (const int*)d_in[1];
    const float* CB  = (const float*)d_in[2];
    float* out = (float*)d_out;

    char* w = (char*)d_ws;
    size_t off = 0;
    unsigned short* embT = (unsigned short*)(w + off); off += (size_t)NPAD_ * C_ * 2;
    unsigned short* CBh  = (unsigned short*)(w + off); off += (size_t)V_ * C_ * 2;
    float* csq = (float*)(w + off); off += (size_t)V_ * 4;
    float* esq = (float*)(w + off); off += (size_t)N_ * 4;
    off = (off + 255) & ~(size_t)255;
    float2* pairbuf = (float2*)(w + off); off += (size_t)N_ * 8;
    unsigned short* dotbuf = (unsigned short*)(w + off);

    size_t avail = (ws_size > off) ? ws_size - off : 0;
    long maxrows = (long)(avail / ((size_t)V_ * 2));
    int chunk = (maxrows >= N_) ? N_ : (int)maxrows;
    if (chunk < 4) chunk = 4;

    hipMemsetAsync(esq, 0, (size_t)N_ * 4, stream);
    hipLaunchKernelGGL(cbconv_kernel, dim3(V_/4), dim3(256), 0, stream, CB, CBh, csq);
    hipLaunchKernelGGL(transpose_conv_kernel, dim3((T_+31)/32, C_/32, B_), dim3(32, 8), 0, stream,
                       S, embT, esq);

    for (int row_lo = 0; row_lo < N_; row_lo += chunk){
        int row_hi = row_lo + chunk; if (row_hi > N_) row_hi = N_;
        int rows = row_hi - row_lo;
        hipLaunchKernelGGL(gemm_dot_kernel, dim3((rows + 127)/128, V_/128), dim3(256), 0, stream,
                           embT, CBh, dotbuf, row_lo, row_hi);
        hipLaunchKernelGGL(select_kernel, dim3((rows + 3)/4), dim3(256), 0, stream,
                           dotbuf, codes, esq, csq, pairbuf, row_lo, rows);
    }
    hipLaunchKernelGGL(finalize_kernel, dim3(1), dim3(1024), 0, stream, pairbuf, out);
}

// Round 4
// 227.685 us; speedup vs baseline: 1.0100x; 1.0100x over previous
//
#include <hip/hip_runtime.h>
#include <hip/hip_bf16.h>
#include <cstdint>

#define B_ 8
#define C_ 512
#define T_ 1500
#define N_ (B_*T_)      // 12000 tokens
#define NPAD_ 12032     // 47*256
#define V_ 4096
#define K_ 100

typedef unsigned long long u64;
typedef __attribute__((ext_vector_type(8))) short short8;
typedef __attribute__((ext_vector_type(8))) unsigned short u16x8;
typedef __attribute__((ext_vector_type(4))) float f32x4;

__device__ __forceinline__ unsigned short f2bf(float x){
    __hip_bfloat16 h = __float2bfloat16(x);
    return __builtin_bit_cast(unsigned short, h);
}
__device__ __forceinline__ unsigned short f2h(float x){
    return __builtin_bit_cast(unsigned short, (_Float16)x);
}
__device__ __forceinline__ float h2f(unsigned short h){
    return (float)__builtin_bit_cast(_Float16, h);
}

__device__ __forceinline__ void gll16(const unsigned short* g, unsigned short* l){
    __builtin_amdgcn_global_load_lds(
        (const __attribute__((address_space(1))) void*)g,
        (__attribute__((address_space(3))) void*)l, 16, 0, 0);
}

// ---------------- codebook: fp32 -> bf16 + csq (fp32-exact) ----------------
__global__ __launch_bounds__(256) void cbconv_kernel(const float* __restrict__ CB,
                                                     unsigned short* __restrict__ CBh,
                                                     float* __restrict__ csq){
    int wv = threadIdx.x >> 6, lane = threadIdx.x & 63;
    int r = blockIdx.x * 4 + wv;
    const float4* p4 = (const float4*)(CB + (size_t)r * C_);
    ushort4* o4 = (ushort4*)(CBh + (size_t)r * C_);
    float s = 0.f;
    #pragma unroll
    for (int j = 0; j < 2; ++j){
        float4 v = p4[lane + j*64];
        s += v.x*v.x + v.y*v.y + v.z*v.z + v.w*v.w;
        ushort4 h; h.x = f2bf(v.x); h.y = f2bf(v.y); h.z = f2bf(v.z); h.w = f2bf(v.w);
        o4[lane + j*64] = h;
    }
    #pragma unroll
    for (int o = 32; o; o >>= 1) s += __shfl_down(s, o, 64);
    if (lane == 0) csq[r] = s;
}

// ---------------- student: (B,C,T) fp32 -> embT bf16 (N,C) + esq partials ----------------
__global__ __launch_bounds__(256) void transpose_conv_kernel(const float* __restrict__ S,
                                                             unsigned short* __restrict__ embT,
                                                             float* __restrict__ esq){
    __shared__ float tile[32][33];
    __shared__ float psum[8][33];
    int b  = blockIdx.z;
    int c0 = blockIdx.y * 32;
    int t0 = blockIdx.x * 32;
    int tx = threadIdx.x, ty = threadIdx.y; // 32 x 8
    #pragma unroll
    for (int r = 0; r < 4; ++r){
        int c = c0 + ty + r*8;
        int t = t0 + tx;
        tile[ty + r*8][tx] = (t < T_) ? S[((size_t)b*C_ + c)*T_ + t] : 0.f;
    }
    __syncthreads();
    float ps = 0.f;
    #pragma unroll
    for (int r = 0; r < 4; ++r){ float v = tile[ty + r*8][tx]; ps += v * v; }
    psum[ty][tx] = ps;
    #pragma unroll
    for (int r = 0; r < 4; ++r){
        int t = t0 + ty + r*8;
        int c = c0 + tx;
        if (t < T_) embT[((size_t)b*T_ + t)*C_ + c] = f2bf(tile[tx][ty + r*8]);
    }
    __syncthreads();
    if (ty == 0){
        int t = t0 + tx;
        if (t < T_){
            float s2 = 0.f;
            #pragma unroll
            for (int w = 0; w < 8; ++w) s2 += psum[w][tx];
            atomicAdd(&esq[b*T_ + t], s2);
        }
    }
}

// ---------------- bf16 MFMA GEMM -> fp16 dot matrix ----------------
// 256x256 tile, BK=32, 16 K-tiles, QUAD-buffered LDS (4 x 32KB = 128KB dynamic),
// stage-2-ahead via global_load_lds, counted vmcnt(4) once per K-tile (never 0
// until the final drain), 2 phases/K-tile x 16 MFMA with s_setprio, both-sides
// slot-XOR LDS swizzle (pre-swizzled global source, XOR'd ds_read -> 2-way free).
// 8 waves (2 wm x 4 wn), per-wave output 128 rows x 64 cols. Operand-swapped
// MFMA so each lane stores 4 consecutive codebook cols as one ushort4.
__global__ __launch_bounds__(512, 2) void gemm_dot_kernel(
    const unsigned short* __restrict__ A, const unsigned short* __restrict__ Bm,
    unsigned short* __restrict__ doth, int row_lo, int row_hi)
{
    extern __shared__ unsigned short lds[];   // 65536 ushort = 128 KB
    // layout (ushort units): A slot s: [s*8192 .. +8192) = 256 rows x 32
    //                        B slot s: [32768 + s*8192 ..)
    int tid = threadIdx.x, lane = tid & 63, wv = tid >> 6;
    int wm = wv >> 2, wn = wv & 3;
    int row0 = row_lo + blockIdx.x * 256;
    int col0 = blockIdx.y * 256;

    // ---- staging source pointers (2 gll16 rounds for A, 2 for B per K-tile) ----
    // wave writes 16 rows x 64B per gll16; lane l -> row l>>2, phys slot l&3.
    // source col slot pre-swizzled so phys slot p at row r holds global slot
    // p ^ (r&3) ^ ((r>>2)&3)  (base rows are multiples of 16 -> lane-only const).
    int l2 = lane >> 2;
    int swz = (((lane & 3) ^ (l2 & 3) ^ ((lane >> 4) & 3)) << 3);  // elem col
    const unsigned short* ApS[2]; const unsigned short* BpS[2];
    #pragma unroll
    for (int r = 0; r < 2; ++r){
        int ra = row0 + r*128 + wv*16 + l2;
        int ca = (ra < N_) ? ra : N_-1;
        ApS[r] = A  + (size_t)ca * C_ + swz;
        BpS[r] = Bm + (size_t)(col0 + r*128 + wv*16 + l2) * C_ + swz;
    }

    // ---- read-side addressing: row R, global k-slot q -> phys slot q^(R&3)^((R>>2)&3)
    int fr = lane & 15;
    int q  = lane >> 4;
    int rsw = ((q ^ (fr & 3) ^ ((fr >> 2) & 3)) << 3);   // elem offset in row
    int aBase = (wm*128 + fr)*32 + rsw;                  // + s*8192 + i*512
    int bBase = 32768 + (wn*64 + fr)*32 + rsw;           // + s*8192 + j*512

    f32x4 acc[8][4];
    #pragma unroll
    for (int i = 0; i < 8; ++i)
        #pragma unroll
        for (int j = 0; j < 4; ++j) acc[i][j] = (f32x4){0.f, 0.f, 0.f, 0.f};

    auto stageA = [&](int kt){
        int s = kt & 3, k0 = kt * 32;
        gll16(ApS[0] + k0, &lds[s*8192 +        wv*512]);
        gll16(ApS[1] + k0, &lds[s*8192 + 4096 + wv*512]);
    };
    auto stageB = [&](int kt){
        int s = kt & 3, k0 = kt * 32;
        gll16(BpS[0] + k0, &lds[32768 + s*8192 +        wv*512]);
        gll16(BpS[1] + k0, &lds[32768 + s*8192 + 4096 + wv*512]);
    };

    // ---- prologue: two K-tiles in flight; drain tile 0, keep tile 1 flying ----
    stageA(0); stageB(0);
    stageA(1); stageB(1);
    asm volatile("s_waitcnt vmcnt(4)" ::: "memory");
    __builtin_amdgcn_s_barrier();

    auto tile = [&](int kt, bool doStage, int vm){
        int s = kt & 3;
        const unsigned short* Al = &lds[s*8192 + aBase];
        const unsigned short* Bl = &lds[s*8192 + bBase];
        short8 a[4], b[4];
        // ---- phase A: reads (af i0-3, bf j0-3) || stage A(kt+2) ----
        #pragma unroll
        for (int j = 0; j < 4; ++j) b[j] = *(const short8*)(Bl + j*512);
        #pragma unroll
        for (int i = 0; i < 4; ++i) a[i] = *(const short8*)(Al + i*512);
        if (doStage) stageA(kt + 2);
        __builtin_amdgcn_s_barrier();
        __builtin_amdgcn_s_setprio(1);
        #pragma unroll
        for (int i = 0; i < 4; ++i)
            #pragma unroll
            for (int j = 0; j < 4; ++j)
                acc[i][j] = __builtin_amdgcn_mfma_f32_16x16x32_bf16(b[j], a[i], acc[i][j], 0, 0, 0);
        __builtin_amdgcn_s_setprio(0);
        __builtin_amdgcn_s_barrier();
        // ---- phase B: reads (af i4-7) || stage B(kt+2); counted vmcnt at tile end ----
        #pragma unroll
        for (int i = 0; i < 4; ++i) a[i] = *(const short8*)(Al + (4+i)*512);
        if (doStage) stageB(kt + 2);
        if (vm == 4) asm volatile("s_waitcnt vmcnt(4)" ::: "memory");
        else if (vm == 0) asm volatile("s_waitcnt vmcnt(0)" ::: "memory");
        __builtin_amdgcn_s_barrier();
        __builtin_amdgcn_s_setprio(1);
        #pragma unroll
        for (int i = 0; i < 4; ++i)
            #pragma unroll
            for (int j = 0; j < 4; ++j)
                acc[4+i][j] = __builtin_amdgcn_mfma_f32_16x16x32_bf16(b[j], a[i], acc[4+i][j], 0, 0, 0);
        __builtin_amdgcn_s_setprio(0);
        __builtin_amdgcn_s_barrier();
    };

    for (int kt = 0; kt < 14; ++kt) tile(kt, true, 4);
    tile(14, false, 0);
    tile(15, false, -1);

    // ---- epilogue: direct ushort4 stores (4 consecutive cb cols per lane) ----
    // n = row0 + wm*128 + i*16 + (lane&15); v = col0 + wn*64 + j*16 + q*4 + reg
    #pragma unroll
    for (int i = 0; i < 8; ++i){
        int n = row0 + wm*128 + i*16 + fr;
        if (n >= row_hi) continue;
        size_t base = (size_t)(n - row_lo) * V_ + col0 + wn*64 + q*4;
        #pragma unroll
        for (int j = 0; j < 4; ++j){
            ushort4 h;
            h.x = f2h(acc[i][j][0]);
            h.y = f2h(acc[i][j][1]);
            h.z = f2h(acc[i][j][2]);
            h.w = f2h(acc[i][j][3]);
            *(ushort4*)&doth[base + j*16] = h;
        }
    }
}

// ---------------- selection v4: wave/row, fp16 dot input, no spills ----------------
__global__ __launch_bounds__(256, 2) void select_kernel(const unsigned short* __restrict__ doth,
                                                        const int* __restrict__ codes,
                                                        const float* __restrict__ esq,
                                                        const float* __restrict__ csq,
                                                        float2* __restrict__ pairbuf,
                                                        int row_lo, int nrows){
    int tid = threadIdx.x, lane = tid & 63, wv = tid >> 6;
    int lrow = blockIdx.x * 4 + wv;
    if (lrow >= nrows) return;               // wave-uniform, no barriers below
    int n = row_lo + lrow;
    const u16x8* r8 = (const u16x8*)(doth + (size_t)lrow * V_);

    __shared__ unsigned hist[4][256] __attribute__((aligned(16)));
    __shared__ unsigned coll[4][64];
    __shared__ unsigned collcnt[4];

    float esq_n = esq[n];
    int code = codes[n];
    float dotc = h2f(doth[(size_t)lrow * V_ + code]);
    unsigned ucode = __float_as_uint(fmaxf(esq_n + csq[code] - 2.f * dotc, 0.f));

    // ---- load + reconstruct d2 bits: u[64] is the only big live array ----
    unsigned u[64];
    #pragma unroll
    for (int j = 0; j < 8; ++j){
        u16x8 h = r8[lane + j*64];
        const float4* cp = (const float4*)(csq + 8*lane + 512*j);
        float4 c0 = cp[0], c1 = cp[1];
        float cs[8] = {c0.x, c0.y, c0.z, c0.w, c1.x, c1.y, c1.z, c1.w};
        #pragma unroll
        for (int e = 0; e < 8; ++e){
            float d2 = fmaxf(esq_n + cs[e] - 2.f * h2f(h[e]), 0.f);
            u[8*j+e] = __float_as_uint(d2);
        }
    }

    // ---- min/max (uint order == float order, all >= 0) ----
    unsigned umin = u[0], umax = u[0];
    #pragma unroll
    for (int k = 1; k < 64; ++k){
        umin = (u[k] < umin) ? u[k] : umin;
        umax = (u[k] > umax) ? u[k] : umax;
    }
    #pragma unroll
    for (int o = 32; o; o >>= 1){
        unsigned a = (unsigned)__shfl_xor((int)umin, o, 64); if (a < umin) umin = a;
        unsigned b = (unsigned)__shfl_xor((int)umax, o, 64); if (b > umax) umax = b;
    }
    // ---- argmin (lowest index among value==umin); v = 8*lane + 512*(k>>3) + (k&7) ----
    unsigned im = 0xFFFFFFFFu;
    #pragma unroll
    for (int k = 0; k < 64; ++k){
        unsigned idx = 8u*(unsigned)lane + (unsigned)(512*(k >> 3) + (k & 7));
        if (u[k] == umin && idx < im) im = idx;
    }
    #pragma unroll
    for (int o = 32; o; o >>= 1){
        unsigned a = (unsigned)__shfl_xor((int)im, o, 64); if (a < im) im = a;
    }
    int idx0 = (int)im;
    float d0 = sqrtf(__uint_as_float(umin));

    // ---- rank-99 threshold t via per-wave histogram + in-bin bitwise search ----
    unsigned t;
    if (umin == umax){
        t = umin;
    } else {
        ((uint4*)&hist[wv][0])[lane] = (uint4){0u,0u,0u,0u};
        if (lane == 0) collcnt[wv] = 0u;
        asm volatile("s_waitcnt lgkmcnt(0)" ::: "memory");
        float fmn = __uint_as_float(umin), fmx = __uint_as_float(umax);
        float invw = 256.0f / (fmx - fmn);
        #pragma unroll
        for (int k = 0; k < 64; ++k){
            float fk = __uint_as_float(u[k]);
            int b = (int)((fk - fmn) * invw); b = (b > 255) ? 255 : b;
            atomicAdd(&hist[wv][b], 1u);
        }
        asm volatile("s_waitcnt lgkmcnt(0)" ::: "memory");
        uint4 hq = ((uint4*)&hist[wv][0])[lane];
        unsigned lsum = hq.x + hq.y + hq.z + hq.w;
        unsigned inc = lsum;
        #pragma unroll
        for (int o = 1; o < 64; o <<= 1){
            unsigned y = (unsigned)__shfl_up((int)inc, o, 64);
            if (lane >= o) inc += y;
        }
        unsigned e0 = inc - lsum;
        unsigned e1 = e0 + hq.x, e2 = e1 + hq.y, e3 = e2 + hq.z, e4 = e3 + hq.w;
        int sel = -1;
        if      (e0 <= 99u && 99u < e1) sel = 0;
        else if (e1 <= 99u && 99u < e2) sel = 1;
        else if (e2 <= 99u && 99u < e3) sel = 2;
        else if (e3 <= 99u && 99u < e4) sel = 3;
        u64 bal = __ballot(sel >= 0);
        int src = __ffsll(bal) - 1;
        unsigned myBk = (unsigned)(4*lane + (sel < 0 ? 0 : sel));
        unsigned myBase = (sel == 1) ? e1 : (sel == 2) ? e2 : (sel == 3) ? e3 : e0;
        int Bk   = __shfl((int)myBk,   src, 64);
        int base = __shfl((int)myBase, src, 64);
        int rk = 99 - base;
        #pragma unroll
        for (int k = 0; k < 64; ++k){
            float fk = __uint_as_float(u[k]);
            int b = (int)((fk - fmn) * invw); b = (b > 255) ? 255 : b;
            if (b == Bk){
                unsigned pos = atomicAdd(&collcnt[wv], 1u);
                if (pos < 64u) coll[wv][pos] = u[k];
            }
        }
        asm volatile("s_waitcnt lgkmcnt(0)" ::: "memory");
        unsigned bcnt = collcnt[wv];
        if (bcnt <= 64u){
            unsigned w = (lane < (int)bcnt) ? coll[wv][lane] : 0xFFFFFFFFu;
            unsigned wmn = (lane < (int)bcnt) ? w : 0xFFFFFFFFu;
            unsigned wmx = (lane < (int)bcnt) ? w : 0u;
            #pragma unroll
            for (int o = 32; o; o >>= 1){
                unsigned a = (unsigned)__shfl_xor((int)wmn, o, 64); if (a < wmn) wmn = a;
                unsigned b = (unsigned)__shfl_xor((int)wmx, o, 64); if (b > wmx) wmx = b;
            }
            unsigned P;
            if (wmn == wmx) P = wmn;
            else {
                int hb = 31 - __clz((int)(wmn ^ wmx));
                unsigned mask = (hb == 31) ? 0xFFFFFFFFu : ((1u << (hb+1)) - 1u);
                P = wmn & ~mask;
                for (int b = hb; b >= 0; --b){
                    unsigned cand = P | (1u << b);
                    int c = __popcll(__ballot(w < cand));
                    if (c <= rk) P = cand;
                }
            }
            t = P;
        } else {
            int hb = 31 - __clz((int)(umin ^ umax));
            unsigned mask = (hb == 31) ? 0xFFFFFFFFu : ((1u << (hb+1)) - 1u);
            unsigned P = umin & ~mask;
            for (int b = hb; b >= 0; --b){
                unsigned cand = P | (1u << b);
                int c = 0;
                #pragma unroll
                for (int k = 0; k < 64; ++k) c += (u[k] < cand) ? 1 : 0;
                #pragma unroll
                for (int o = 32; o; o >>= 1) c += __shfl_xor(c, o, 64);
                if (c <= 99) P = cand;
            }
            t = P;
        }
    }
    float tval = sqrtf(__uint_as_float(t));

    // ---- softmax denom over top-100 (tie multiplicity at t) ----
    float s = 0.f; int cl = 0;
    #pragma unroll
    for (int k = 0; k < 64; ++k){
        if (u[k] < t){ s += __expf(d0 - sqrtf(__uint_as_float(u[k]))); cl++; }
    }
    #pragma unroll
    for (int o = 32; o; o >>= 1){
        s += __shfl_xor(s, o, 64);
        cl += __shfl_xor(cl, o, 64);
    }
    if (lane == 0){
        float S = s + (float)(K_ - cl) * __expf(d0 - tval);
        float dcode = sqrtf(__uint_as_float(ucode));
        if (ucode > t) S += __expf(d0 - dcode) - __expf(d0 - tval);  // include_correct swap
        float nll = dcode - d0 + __logf(S);
        pairbuf[n] = make_float2(nll, (idx0 == code) ? 1.f : 0.f);
    }
}

__global__ __launch_bounds__(1024) void finalize_kernel(const float2* __restrict__ pair,
                                                        float* __restrict__ out){
    int tid = threadIdx.x;
    float sn = 0.f, sh = 0.f;
    for (int i = tid; i < N_; i += 1024){
        float2 p = pair[i]; sn += p.x; sh += p.y;
    }
    #pragma unroll
    for (int o = 32; o; o >>= 1){ sn += __shfl_down(sn, o, 64); sh += __shfl_down(sh, o, 64); }
    __shared__ float a[16], b[16];
    int wv = tid >> 6, lane = tid & 63;
    if (lane == 0){ a[wv] = sn; b[wv] = sh; }
    __syncthreads();
    if (tid == 0){
        float L = 0.f, H = 0.f;
        #pragma unroll
        for (int i = 0; i < 16; ++i){ L += a[i]; H += b[i]; }
        out[0] = L / (float)N_;
        out[1] = H / (float)N_;   // local prediction is always candidate 0
        out[2] = H / (float)N_;
        out[3] = 1.0f;            // include_correct guarantees membership
    }
}

// ---------------- launcher ----------------
extern "C" void kernel_launch(void* const* d_in, const int* in_sizes, int n_in,
                              void* d_out, int out_size, void* d_ws, size_t ws_size,
                              hipStream_t stream){
    const float* S   = (const float*)d_in[0];
    const int* codes = (const int*)d_in[1];
    const float* CB  = (const float*)d_in[2];
    float* out = (float*)d_out;

    char* w = (char*)d_ws;
    size_t off = 0;
    unsigned short* embT = (unsigned short*)(w + off); off += (size_t)NPAD_ * C_ * 2;
    unsigned short* CBh  = (unsigned short*)(w + off); off += (size_t)V_ * C_ * 2;
    float* csq = (float*)(w + off); off += (size_t)V_ * 4;
    float* esq = (float*)(w + off); off += (size_t)N_ * 4;
    off = (off + 255) & ~(size_t)255;
    float2* pairbuf = (float2*)(w + off); off += (size_t)N_ * 8;
    unsigned short* dotbuf = (unsigned short*)(w + off);

    size_t avail = (ws_size > off) ? ws_size - off : 0;
    long maxrows = (long)(avail / ((size_t)V_ * 2));
    int chunk = (maxrows >= N_) ? N_ : (int)maxrows;
    if (chunk < 4) chunk = 4;

    hipMemsetAsync(esq, 0, (size_t)N_ * 4, stream);
    hipLaunchKernelGGL(cbconv_kernel, dim3(V_/4), dim3(256), 0, stream, CB, CBh, csq);
    hipLaunchKernelGGL(transpose_conv_kernel, dim3((T_+31)/32, C_/32, B_), dim3(32, 8), 0, stream,
                       S, embT, esq);

    for (int row_lo = 0; row_lo < N_; row_lo += chunk){
        int row_hi = row_lo + chunk; if (row_hi > N_) row_hi = N_;
        int rows = row_hi - row_lo;
        hipLaunchKernelGGL(gemm_dot_kernel, dim3((rows + 255)/256, V_/256), dim3(512),
                           131072, stream, embT, CBh, dotbuf, row_lo, row_hi);
        hipLaunchKernelGGL(select_kernel, dim3((rows + 3)/4), dim3(256), 0, stream,
                           dotbuf, codes, esq, csq, pairbuf, row_lo, rows);
    }
    hipLaunchKernelGGL(finalize_kernel, dim3(1), dim3(1024), 0, stream, pairbuf, out);
}

// Round 5
// 225.254 us; speedup vs baseline: 1.0209x; 1.0108x over previous
//
#include <hip/hip_runtime.h>
#include <hip/hip_bf16.h>
#include <cstdint>

#define B_ 8
#define C_ 512
#define T_ 1500
#define N_ (B_*T_)      // 12000 tokens
#define NPAD_ 12032
#define V_ 4096
#define K_ 100

typedef unsigned long long u64;
typedef __attribute__((ext_vector_type(8))) short short8;
typedef __attribute__((ext_vector_type(8))) unsigned short u16x8;
typedef __attribute__((ext_vector_type(4))) float f32x4;

__device__ __forceinline__ unsigned short f2bf(float x){
    __hip_bfloat16 h = __float2bfloat16(x);
    return __builtin_bit_cast(unsigned short, h);
}
__device__ __forceinline__ unsigned short f2h(float x){
    return __builtin_bit_cast(unsigned short, (_Float16)x);
}
__device__ __forceinline__ float h2f(unsigned short h){
    return (float)__builtin_bit_cast(_Float16, h);
}

__device__ __forceinline__ void gll16(const unsigned short* g, unsigned short* l){
    __builtin_amdgcn_global_load_lds(
        (const __attribute__((address_space(1))) void*)g,
        (__attribute__((address_space(3))) void*)l, 16, 0, 0);
}

// ---------------- codebook: fp32 -> bf16 + csq (fp32-exact) ----------------
__global__ __launch_bounds__(256) void cbconv_kernel(const float* __restrict__ CB,
                                                     unsigned short* __restrict__ CBh,
                                                     float* __restrict__ csq){
    int wv = threadIdx.x >> 6, lane = threadIdx.x & 63;
    int r = blockIdx.x * 4 + wv;
    const float4* p4 = (const float4*)(CB + (size_t)r * C_);
    ushort4* o4 = (ushort4*)(CBh + (size_t)r * C_);
    float s = 0.f;
    #pragma unroll
    for (int j = 0; j < 2; ++j){
        float4 v = p4[lane + j*64];
        s += v.x*v.x + v.y*v.y + v.z*v.z + v.w*v.w;
        ushort4 h; h.x = f2bf(v.x); h.y = f2bf(v.y); h.z = f2bf(v.z); h.w = f2bf(v.w);
        o4[lane + j*64] = h;
    }
    #pragma unroll
    for (int o = 32; o; o >>= 1) s += __shfl_down(s, o, 64);
    if (lane == 0) csq[r] = s;
}

// ---------------- student: (B,C,T) fp32 -> embT bf16 (N,C) + esq partials ----------------
__global__ __launch_bounds__(256) void transpose_conv_kernel(const float* __restrict__ S,
                                                             unsigned short* __restrict__ embT,
                                                             float* __restrict__ esq){
    __shared__ float tile[32][33];
    __shared__ float psum[8][33];
    int b  = blockIdx.z;
    int c0 = blockIdx.y * 32;
    int t0 = blockIdx.x * 32;
    int tx = threadIdx.x, ty = threadIdx.y; // 32 x 8
    #pragma unroll
    for (int r = 0; r < 4; ++r){
        int c = c0 + ty + r*8;
        int t = t0 + tx;
        tile[ty + r*8][tx] = (t < T_) ? S[((size_t)b*C_ + c)*T_ + t] : 0.f;
    }
    __syncthreads();
    float ps = 0.f;
    #pragma unroll
    for (int r = 0; r < 4; ++r){ float v = tile[ty + r*8][tx]; ps += v * v; }
    psum[ty][tx] = ps;
    #pragma unroll
    for (int r = 0; r < 4; ++r){
        int t = t0 + ty + r*8;
        int c = c0 + tx;
        if (t < T_) embT[((size_t)b*T_ + t)*C_ + c] = f2bf(tile[tx][ty + r*8]);
    }
    __syncthreads();
    if (ty == 0){
        int t = t0 + tx;
        if (t < T_){
            float s2 = 0.f;
            #pragma unroll
            for (int w = 0; w < 8; ++w) s2 += psum[w][tx];
            atomicAdd(&esq[b*T_ + t], s2);
        }
    }
}

// ---------------- bf16 MFMA GEMM -> fp16 dot matrix (r2-proven 2-barrier 128^2) ----------------
__global__ __launch_bounds__(256) void gemm_dot_kernel(
    const unsigned short* __restrict__ A, const unsigned short* __restrict__ Bm,
    unsigned short* __restrict__ doth, int row_lo, int row_hi)
{
    __shared__ unsigned short smem[128*136];   // 34816 B; staging (16 KB) aliased in front
    unsigned short* As = smem;                 // 128*32
    unsigned short* Bs = smem + 128*32;        // 128*32
    int tid = threadIdx.x, lane = tid & 63, wv = tid >> 6;
    int row0 = row_lo + blockIdx.x * 128;
    int col0 = blockIdx.y * 128;

    int sr = lane >> 2;
    int sk = (lane & 3) * 8;
    int ar0 = row0 + wv*32 + sr;       int ar1 = ar0 + 16;
    int ca0 = (ar0 < N_) ? ar0 : N_-1; int ca1 = (ar1 < N_) ? ar1 : N_-1;
    const unsigned short* Ap0 = A  + (size_t)ca0 * C_ + sk;
    const unsigned short* Ap1 = A  + (size_t)ca1 * C_ + sk;
    const unsigned short* Bp0 = Bm + (size_t)(col0 + wv*32 + sr) * C_ + sk;
    const unsigned short* Bp1 = Bp0 + (size_t)16 * C_;
    unsigned short* Ad0 = &As[(wv*32     ) * 32];
    unsigned short* Ad1 = &As[(wv*32 + 16) * 32];
    unsigned short* Bd0 = &Bs[(wv*32     ) * 32];
    unsigned short* Bd1 = &Bs[(wv*32 + 16) * 32];

    int wm = (wv >> 1) * 64, wn = (wv & 1) * 64;
    int fr = lane & 15;
    int fk = (lane >> 4) * 8;

    f32x4 acc[4][4];
    #pragma unroll
    for (int i = 0; i < 4; ++i)
        #pragma unroll
        for (int j = 0; j < 4; ++j) acc[i][j] = (f32x4){0.f, 0.f, 0.f, 0.f};

    for (int kt = 0; kt < C_/32; ++kt){
        int k0 = kt * 32;
        gll16(Ap0 + k0, Ad0);
        gll16(Ap1 + k0, Ad1);
        gll16(Bp0 + k0, Bd0);
        gll16(Bp1 + k0, Bd1);
        __syncthreads();
        short8 af[4], bf[4];
        #pragma unroll
        for (int i = 0; i < 4; ++i) af[i] = *(const short8*)&As[(wm + i*16 + fr)*32 + fk];
        #pragma unroll
        for (int j = 0; j < 4; ++j) bf[j] = *(const short8*)&Bs[(wn + j*16 + fr)*32 + fk];
        #pragma unroll
        for (int i = 0; i < 4; ++i)
            #pragma unroll
            for (int j = 0; j < 4; ++j)
                acc[i][j] = __builtin_amdgcn_mfma_f32_16x16x32_bf16(bf[j], af[i], acc[i][j], 0, 0, 0);
        __syncthreads();
    }
    // loop ends with a barrier: safe to alias smem for the out-tile.

    // ---- stage 1: pack fp16 into LDS out-tile [128][136] ----
    const int LD = 136;
    int en = lane & 15;
    int ev = (lane >> 4) * 4;
    #pragma unroll
    for (int i = 0; i < 4; ++i){
        int r = wm + i*16 + en;
        #pragma unroll
        for (int j = 0; j < 4; ++j){
            ushort4 h;
            h.x = f2h(acc[i][j][0]);
            h.y = f2h(acc[i][j][1]);
            h.z = f2h(acc[i][j][2]);
            h.w = f2h(acc[i][j][3]);
            *(ushort4*)&smem[r*LD + wn + j*16 + ev] = h;
        }
    }
    __syncthreads();

    // ---- stage 2: coalesced stores, 16 lanes cover one row's 256B ----
    int rr = tid >> 4;          // 0..15
    int cc = (tid & 15) * 8;    // element col, 16B per lane
    #pragma unroll
    for (int it = 0; it < 8; ++it){
        int r = it*16 + rr;
        int n = row0 + r;
        if (n < row_hi){
            u16x8 v = *(const u16x8*)&smem[r*LD + cc];
            *(u16x8*)&doth[(size_t)(n - row_lo) * V_ + col0 + cc] = v;
        }
    }
}

// ---------------- selection v4: wave/row, fp16 dot input, no spills ----------------
__global__ __launch_bounds__(256, 2) void select_kernel(const unsigned short* __restrict__ doth,
                                                        const int* __restrict__ codes,
                                                        const float* __restrict__ esq,
                                                        const float* __restrict__ csq,
                                                        float2* __restrict__ pairbuf,
                                                        int row_lo, int nrows){
    int tid = threadIdx.x, lane = tid & 63, wv = tid >> 6;
    int lrow = blockIdx.x * 4 + wv;
    if (lrow >= nrows) return;               // wave-uniform, no barriers below
    int n = row_lo + lrow;
    const u16x8* r8 = (const u16x8*)(doth + (size_t)lrow * V_);

    __shared__ unsigned hist[4][256] __attribute__((aligned(16)));
    __shared__ unsigned coll[4][64];
    __shared__ unsigned collcnt[4];

    float esq_n = esq[n];
    int code = codes[n];
    float dotc = h2f(doth[(size_t)lrow * V_ + code]);
    unsigned ucode = __float_as_uint(fmaxf(esq_n + csq[code] - 2.f * dotc, 0.f));

    // ---- load + reconstruct d2 bits: u[64] is the only big live array ----
    unsigned u[64];
    #pragma unroll
    for (int j = 0; j < 8; ++j){
        u16x8 h = r8[lane + j*64];
        const float4* cp = (const float4*)(csq + 8*lane + 512*j);
        float4 c0 = cp[0], c1 = cp[1];
        float cs[8] = {c0.x, c0.y, c0.z, c0.w, c1.x, c1.y, c1.z, c1.w};
        #pragma unroll
        for (int e = 0; e < 8; ++e){
            float d2 = fmaxf(esq_n + cs[e] - 2.f * h2f(h[e]), 0.f);
            u[8*j+e] = __float_as_uint(d2);
        }
    }

    // ---- min/max (uint order == float order, all >= 0) ----
    unsigned umin = u[0], umax = u[0];
    #pragma unroll
    for (int k = 1; k < 64; ++k){
        umin = (u[k] < umin) ? u[k] : umin;
        umax = (u[k] > umax) ? u[k] : umax;
    }
    #pragma unroll
    for (int o = 32; o; o >>= 1){
        unsigned a = (unsigned)__shfl_xor((int)umin, o, 64); if (a < umin) umin = a;
        unsigned b = (unsigned)__shfl_xor((int)umax, o, 64); if (b > umax) umax = b;
    }
    // ---- argmin (lowest index among value==umin); v = 8*lane + 512*(k>>3) + (k&7) ----
    unsigned im = 0xFFFFFFFFu;
    #pragma unroll
    for (int k = 0; k < 64; ++k){
        unsigned idx = 8u*(unsigned)lane + (unsigned)(512*(k >> 3) + (k & 7));
        if (u[k] == umin && idx < im) im = idx;
    }
    #pragma unroll
    for (int o = 32; o; o >>= 1){
        unsigned a = (unsigned)__shfl_xor((int)im, o, 64); if (a < im) im = a;
    }
    int idx0 = (int)im;
    float d0 = sqrtf(__uint_as_float(umin));

    // ---- rank-99 threshold t via per-wave histogram + in-bin bitwise search ----
    unsigned t;
    if (umin == umax){
        t = umin;
    } else {
        ((uint4*)&hist[wv][0])[lane] = (uint4){0u,0u,0u,0u};
        if (lane == 0) collcnt[wv] = 0u;
        asm volatile("s_waitcnt lgkmcnt(0)" ::: "memory");
        float fmn = __uint_as_float(umin), fmx = __uint_as_float(umax);
        float invw = 256.0f / (fmx - fmn);
        #pragma unroll
        for (int k = 0; k < 64; ++k){
            float fk = __uint_as_float(u[k]);
            int b = (int)((fk - fmn) * invw); b = (b > 255) ? 255 : b;
            atomicAdd(&hist[wv][b], 1u);
        }
        asm volatile("s_waitcnt lgkmcnt(0)" ::: "memory");
        uint4 hq = ((uint4*)&hist[wv][0])[lane];
        unsigned lsum = hq.x + hq.y + hq.z + hq.w;
        unsigned inc = lsum;
        #pragma unroll
        for (int o = 1; o < 64; o <<= 1){
            unsigned y = (unsigned)__shfl_up((int)inc, o, 64);
            if (lane >= o) inc += y;
        }
        unsigned e0 = inc - lsum;
        unsigned e1 = e0 + hq.x, e2 = e1 + hq.y, e3 = e2 + hq.z, e4 = e3 + hq.w;
        int sel = -1;
        if      (e0 <= 99u && 99u < e1) sel = 0;
        else if (e1 <= 99u && 99u < e2) sel = 1;
        else if (e2 <= 99u && 99u < e3) sel = 2;
        else if (e3 <= 99u && 99u < e4) sel = 3;
        u64 bal = __ballot(sel >= 0);
        int src = __ffsll(bal) - 1;
        unsigned myBk = (unsigned)(4*lane + (sel < 0 ? 0 : sel));
        unsigned myBase = (sel == 1) ? e1 : (sel == 2) ? e2 : (sel == 3) ? e3 : e0;
        int Bk   = __shfl((int)myBk,   src, 64);
        int base = __shfl((int)myBase, src, 64);
        int rk = 99 - base;
        #pragma unroll
        for (int k = 0; k < 64; ++k){
            float fk = __uint_as_float(u[k]);
            int b = (int)((fk - fmn) * invw); b = (b > 255) ? 255 : b;
            if (b == Bk){
                unsigned pos = atomicAdd(&collcnt[wv], 1u);
                if (pos < 64u) coll[wv][pos] = u[k];
            }
        }
        asm volatile("s_waitcnt lgkmcnt(0)" ::: "memory");
        unsigned bcnt = collcnt[wv];
        if (bcnt <= 64u){
            unsigned w = (lane < (int)bcnt) ? coll[wv][lane] : 0xFFFFFFFFu;
            unsigned wmn = (lane < (int)bcnt) ? w : 0xFFFFFFFFu;
            unsigned wmx = (lane < (int)bcnt) ? w : 0u;
            #pragma unroll
            for (int o = 32; o; o >>= 1){
                unsigned a = (unsigned)__shfl_xor((int)wmn, o, 64); if (a < wmn) wmn = a;
                unsigned b = (unsigned)__shfl_xor((int)wmx, o, 64); if (b > wmx) wmx = b;
            }
            unsigned P;
            if (wmn == wmx) P = wmn;
            else {
                int hb = 31 - __clz((int)(wmn ^ wmx));
                unsigned mask = (hb == 31) ? 0xFFFFFFFFu : ((1u << (hb+1)) - 1u);
                P = wmn & ~mask;
                for (int b = hb; b >= 0; --b){
                    unsigned cand = P | (1u << b);
                    int c = __popcll(__ballot(w < cand));
                    if (c <= rk) P = cand;
                }
            }
            t = P;
        } else {
            int hb = 31 - __clz((int)(umin ^ umax));
            unsigned mask = (hb == 31) ? 0xFFFFFFFFu : ((1u << (hb+1)) - 1u);
            unsigned P = umin & ~mask;
            for (int b = hb; b >= 0; --b){
                unsigned cand = P | (1u << b);
                int c = 0;
                #pragma unroll
                for (int k = 0; k < 64; ++k) c += (u[k] < cand) ? 1 : 0;
                #pragma unroll
                for (int o = 32; o; o >>= 1) c += __shfl_xor(c, o, 64);
                if (c <= 99) P = cand;
            }
            t = P;
        }
    }
    float tval = sqrtf(__uint_as_float(t));

    // ---- softmax denom over top-100 (tie multiplicity at t) ----
    float s = 0.f; int cl = 0;
    #pragma unroll
    for (int k = 0; k < 64; ++k){
        if (u[k] < t){ s += __expf(d0 - sqrtf(__uint_as_float(u[k]))); cl++; }
    }
    #pragma unroll
    for (int o = 32; o; o >>= 1){
        s += __shfl_xor(s, o, 64);
        cl += __shfl_xor(cl, o, 64);
    }
    if (lane == 0){
        float S = s + (float)(K_ - cl) * __expf(d0 - tval);
        float dcode = sqrtf(__uint_as_float(ucode));
        if (ucode > t) S += __expf(d0 - dcode) - __expf(d0 - tval);  // include_correct swap
        float nll = dcode - d0 + __logf(S);
        pairbuf[n] = make_float2(nll, (idx0 == code) ? 1.f : 0.f);
    }
}

__global__ __launch_bounds__(1024) void finalize_kernel(const float2* __restrict__ pair,
                                                        float* __restrict__ out){
    int tid = threadIdx.x;
    float sn = 0.f, sh = 0.f;
    for (int i = tid; i < N_; i += 1024){
        float2 p = pair[i]; sn += p.x; sh += p.y;
    }
    #pragma unroll
    for (int o = 32; o; o >>= 1){ sn += __shfl_down(sn, o, 64); sh += __shfl_down(sh, o, 64); }
    __shared__ float a[16], b[16];
    int wv = tid >> 6, lane = tid & 63;
    if (lane == 0){ a[wv] = sn; b[wv] = sh; }
    __syncthreads();
    if (tid == 0){
        float L = 0.f, H = 0.f;
        #pragma unroll
        for (int i = 0; i < 16; ++i){ L += a[i]; H += b[i]; }
        out[0] = L / (float)N_;
        out[1] = H / (float)N_;   // local prediction is always candidate 0
        out[2] = H / (float)N_;
        out[3] = 1.0f;            // include_correct guarantees membership
    }
}

// ---------------- launcher ----------------
// Diagnostic round: gemm split into 4 dispatches (~21 us each) so select_kernel
// (and anything >23 us) surfaces in the rocprof top-5 with full counters.
// Select runs ONCE over all rows (dotbuf holds the full N x V matrix when ws allows).
extern "C" void kernel_launch(void* const* d_in, const int* in_sizes, int n_in,
                              void* d_out, int out_size, void* d_ws, size_t ws_size,
                              hipStream_t stream){
    const float* S   = (const float*)d_in[0];
    const int* codes = (const int*)d_in[1];
    const float* CB  = (const float*)d_in[2];
    float* out = (float*)d_out;

    char* w = (char*)d_ws;
    size_t off = 0;
    unsigned short* embT = (unsigned short*)(w + off); off += (size_t)NPAD_ * C_ * 2;
    unsigned short* CBh  = (unsigned short*)(w + off); off += (size_t)V_ * C_ * 2;
    float* csq = (float*)(w + off); off += (size_t)V_ * 4;
    float* esq = (float*)(w + off); off += (size_t)N_ * 4;
    off = (off + 255) & ~(size_t)255;
    float2* pairbuf = (float2*)(w + off); off += (size_t)N_ * 8;
    unsigned short* dotbuf = (unsigned short*)(w + off);

    size_t avail = (ws_size > off) ? ws_size - off : 0;
    long maxrows = (long)(avail / ((size_t)V_ * 2));

    hipMemsetAsync(esq, 0, (size_t)N_ * 4, stream);
    hipLaunchKernelGGL(cbconv_kernel, dim3(V_/4), dim3(256), 0, stream, CB, CBh, csq);
    hipLaunchKernelGGL(transpose_conv_kernel, dim3((T_+31)/32, C_/32, B_), dim3(32, 8), 0, stream,
                       S, embT, esq);

    if (maxrows >= N_){
        // full dot matrix fits: 4 gemm sub-dispatches, then one full select
        const int gchunk = 3072;   // multiple of 128
        for (int row_lo = 0; row_lo < N_; row_lo += gchunk){
            int row_hi = row_lo + gchunk; if (row_hi > N_) row_hi = N_;
            int rows = row_hi - row_lo;
            hipLaunchKernelGGL(gemm_dot_kernel, dim3((rows + 127)/128, V_/128), dim3(256), 0, stream,
                               embT, CBh, dotbuf + (size_t)row_lo * V_, row_lo, row_hi);
        }
        hipLaunchKernelGGL(select_kernel, dim3((N_ + 3)/4), dim3(256), 0, stream,
                           dotbuf, codes, esq, csq, pairbuf, 0, N_);
    } else {
        // fallback: chunked gemm+select pairs within available workspace
        int chunk = (int)(maxrows & ~127L);
        if (chunk < 128) chunk = 128;
        for (int row_lo = 0; row_lo < N_; row_lo += chunk){
            int row_hi = row_lo + chunk; if (row_hi > N_) row_hi = N_;
            int rows = row_hi - row_lo;
            hipLaunchKernelGGL(gemm_dot_kernel, dim3((rows + 127)/128, V_/128), dim3(256), 0, stream,
                               embT, CBh, dotbuf, row_lo, row_hi);
            hipLaunchKernelGGL(select_kernel, dim3((rows + 3)/4), dim3(256), 0, stream,
                               dotbuf, codes, esq, csq, pairbuf, row_lo, rows);
        }
    }
    hipLaunchKernelGGL(finalize_kernel, dim3(1), dim3(1024), 0, stream, pairbuf, out);
}

// Round 6
// 213.947 us; speedup vs baseline: 1.0749x; 1.0528x over previous
//
#include <hip/hip_runtime.h>
#include <hip/hip_bf16.h>
#include <cstdint>

#define B_ 8
#define C_ 512
#define T_ 1500
#define N_ (B_*T_)      // 12000 tokens
#define NPAD_ 12032
#define V_ 4096
#define K_ 100

typedef unsigned long long u64;
typedef __attribute__((ext_vector_type(8))) short short8;
typedef __attribute__((ext_vector_type(8))) unsigned short u16x8;
typedef __attribute__((ext_vector_type(4))) float f32x4;

__device__ __forceinline__ unsigned short f2bf(float x){
    __hip_bfloat16 h = __float2bfloat16(x);
    return __builtin_bit_cast(unsigned short, h);
}
__device__ __forceinline__ unsigned short f2h(float x){
    return __builtin_bit_cast(unsigned short, (_Float16)x);
}
__device__ __forceinline__ float h2f(unsigned short h){
    return (float)__builtin_bit_cast(_Float16, h);
}

__device__ __forceinline__ void gll16(const unsigned short* g, unsigned short* l){
    __builtin_amdgcn_global_load_lds(
        (const __attribute__((address_space(1))) void*)g,
        (__attribute__((address_space(3))) void*)l, 16, 0, 0);
}

// ---------------- codebook: fp32 -> bf16 + csq (fp32-exact) ----------------
__global__ __launch_bounds__(256) void cbconv_kernel(const float* __restrict__ CB,
                                                     unsigned short* __restrict__ CBh,
                                                     float* __restrict__ csq){
    int wv = threadIdx.x >> 6, lane = threadIdx.x & 63;
    int r = blockIdx.x * 4 + wv;
    const float4* p4 = (const float4*)(CB + (size_t)r * C_);
    ushort4* o4 = (ushort4*)(CBh + (size_t)r * C_);
    float s = 0.f;
    #pragma unroll
    for (int j = 0; j < 2; ++j){
        float4 v = p4[lane + j*64];
        s += v.x*v.x + v.y*v.y + v.z*v.z + v.w*v.w;
        ushort4 h; h.x = f2bf(v.x); h.y = f2bf(v.y); h.z = f2bf(v.z); h.w = f2bf(v.w);
        o4[lane + j*64] = h;
    }
    #pragma unroll
    for (int o = 32; o; o >>= 1) s += __shfl_down(s, o, 64);
    if (lane == 0) csq[r] = s;
}

// ---------------- student: (B,C,T) fp32 -> embT bf16 (N,C) + esq partials ----------------
__global__ __launch_bounds__(256) void transpose_conv_kernel(const float* __restrict__ S,
                                                             unsigned short* __restrict__ embT,
                                                             float* __restrict__ esq){
    __shared__ float tile[32][33];
    __shared__ float psum[8][33];
    int b  = blockIdx.z;
    int c0 = blockIdx.y * 32;
    int t0 = blockIdx.x * 32;
    int tx = threadIdx.x, ty = threadIdx.y; // 32 x 8
    #pragma unroll
    for (int r = 0; r < 4; ++r){
        int c = c0 + ty + r*8;
        int t = t0 + tx;
        tile[ty + r*8][tx] = (t < T_) ? S[((size_t)b*C_ + c)*T_ + t] : 0.f;
    }
    __syncthreads();
    float ps = 0.f;
    #pragma unroll
    for (int r = 0; r < 4; ++r){ float v = tile[ty + r*8][tx]; ps += v * v; }
    psum[ty][tx] = ps;
    #pragma unroll
    for (int r = 0; r < 4; ++r){
        int t = t0 + ty + r*8;
        int c = c0 + tx;
        if (t < T_) embT[((size_t)b*T_ + t)*C_ + c] = f2bf(tile[tx][ty + r*8]);
    }
    __syncthreads();
    if (ty == 0){
        int t = t0 + tx;
        if (t < T_){
            float s2 = 0.f;
            #pragma unroll
            for (int w = 0; w < 8; ++w) s2 += psum[w][tx];
            atomicAdd(&esq[b*T_ + t], s2);
        }
    }
}

// ---------------- bf16 MFMA GEMM -> fp16 dot matrix (r2-proven 2-barrier 128^2) ----------------
__global__ __launch_bounds__(256) void gemm_dot_kernel(
    const unsigned short* __restrict__ A, const unsigned short* __restrict__ Bm,
    unsigned short* __restrict__ doth, int row_lo, int row_hi)
{
    __shared__ unsigned short smem[128*136];   // 34816 B; staging (16 KB) aliased in front
    unsigned short* As = smem;                 // 128*32
    unsigned short* Bs = smem + 128*32;        // 128*32
    int tid = threadIdx.x, lane = tid & 63, wv = tid >> 6;
    int row0 = row_lo + blockIdx.x * 128;
    int col0 = blockIdx.y * 128;

    int sr = lane >> 2;
    int sk = (lane & 3) * 8;
    int ar0 = row0 + wv*32 + sr;       int ar1 = ar0 + 16;
    int ca0 = (ar0 < N_) ? ar0 : N_-1; int ca1 = (ar1 < N_) ? ar1 : N_-1;
    const unsigned short* Ap0 = A  + (size_t)ca0 * C_ + sk;
    const unsigned short* Ap1 = A  + (size_t)ca1 * C_ + sk;
    const unsigned short* Bp0 = Bm + (size_t)(col0 + wv*32 + sr) * C_ + sk;
    const unsigned short* Bp1 = Bp0 + (size_t)16 * C_;
    unsigned short* Ad0 = &As[(wv*32     ) * 32];
    unsigned short* Ad1 = &As[(wv*32 + 16) * 32];
    unsigned short* Bd0 = &Bs[(wv*32     ) * 32];
    unsigned short* Bd1 = &Bs[(wv*32 + 16) * 32];

    int wm = (wv >> 1) * 64, wn = (wv & 1) * 64;
    int fr = lane & 15;
    int fk = (lane >> 4) * 8;

    f32x4 acc[4][4];
    #pragma unroll
    for (int i = 0; i < 4; ++i)
        #pragma unroll
        for (int j = 0; j < 4; ++j) acc[i][j] = (f32x4){0.f, 0.f, 0.f, 0.f};

    for (int kt = 0; kt < C_/32; ++kt){
        int k0 = kt * 32;
        gll16(Ap0 + k0, Ad0);
        gll16(Ap1 + k0, Ad1);
        gll16(Bp0 + k0, Bd0);
        gll16(Bp1 + k0, Bd1);
        __syncthreads();
        short8 af[4], bf[4];
        #pragma unroll
        for (int i = 0; i < 4; ++i) af[i] = *(const short8*)&As[(wm + i*16 + fr)*32 + fk];
        #pragma unroll
        for (int j = 0; j < 4; ++j) bf[j] = *(const short8*)&Bs[(wn + j*16 + fr)*32 + fk];
        #pragma unroll
        for (int i = 0; i < 4; ++i)
            #pragma unroll
            for (int j = 0; j < 4; ++j)
                acc[i][j] = __builtin_amdgcn_mfma_f32_16x16x32_bf16(bf[j], af[i], acc[i][j], 0, 0, 0);
        __syncthreads();
    }
    // loop ends with a barrier: safe to alias smem for the out-tile.

    // ---- stage 1: pack fp16 into LDS out-tile [128][136] ----
    const int LD = 136;
    int en = lane & 15;
    int ev = (lane >> 4) * 4;
    #pragma unroll
    for (int i = 0; i < 4; ++i){
        int r = wm + i*16 + en;
        #pragma unroll
        for (int j = 0; j < 4; ++j){
            ushort4 h;
            h.x = f2h(acc[i][j][0]);
            h.y = f2h(acc[i][j][1]);
            h.z = f2h(acc[i][j][2]);
            h.w = f2h(acc[i][j][3]);
            *(ushort4*)&smem[r*LD + wn + j*16 + ev] = h;
        }
    }
    __syncthreads();

    // ---- stage 2: coalesced stores, 16 lanes cover one row's 256B ----
    int rr = tid >> 4;          // 0..15
    int cc = (tid & 15) * 8;    // element col, 16B per lane
    #pragma unroll
    for (int it = 0; it < 8; ++it){
        int r = it*16 + rr;
        int n = row0 + r;
        if (n < row_hi){
            u16x8 v = *(const u16x8*)&smem[r*LD + cc];
            *(u16x8*)&doth[(size_t)(n - row_lo) * V_ + col0 + cc] = v;
        }
    }
}

// ---------------- selection v5: compacted softmax, packed bins ----------------
// Per wave = one row of 4096 d2 values (64/lane). Passes:
//  1. reconstruct u[64]  2. merged min/argmin/max  3. histogram (bins packed into
//  16 VGPRs)  4. collect: bin==Bk -> coll, bin<Bk -> coll2 (count == base <= 99)
//  5. in-bin bitwise ballot search for t  6. softmax over COMPACTED values only
//  (<=3 exp/sqrt per lane instead of 64): bins<Bk all < t; bins>Bk all > t.
__global__ __launch_bounds__(256, 2) void select_kernel(const unsigned short* __restrict__ doth,
                                                        const int* __restrict__ codes,
                                                        const float* __restrict__ esq,
                                                        const float* __restrict__ csq,
                                                        float2* __restrict__ pairbuf,
                                                        int row_lo, int nrows){
    int tid = threadIdx.x, lane = tid & 63, wv = tid >> 6;
    int lrow = blockIdx.x * 4 + wv;
    if (lrow >= nrows) return;               // wave-uniform, no barriers below
    int n = row_lo + lrow;
    const u16x8* r8 = (const u16x8*)(doth + (size_t)lrow * V_);

    __shared__ unsigned hist[4][256] __attribute__((aligned(16)));
    __shared__ unsigned coll[4][64];
    __shared__ unsigned coll2[4][128];
    __shared__ unsigned cnts[4][2];          // {coll count, coll2 count}

    float esq_n = esq[n];
    int code = codes[n];
    float dotc = h2f(doth[(size_t)lrow * V_ + code]);
    unsigned ucode = __float_as_uint(fmaxf(esq_n + csq[code] - 2.f * dotc, 0.f));

    // ---- load + reconstruct d2 bits ----
    unsigned u[64];
    #pragma unroll
    for (int j = 0; j < 8; ++j){
        u16x8 h = r8[lane + j*64];
        const float4* cp = (const float4*)(csq + 8*lane + 512*j);
        float4 c0 = cp[0], c1 = cp[1];
        float cs[8] = {c0.x, c0.y, c0.z, c0.w, c1.x, c1.y, c1.z, c1.w};
        #pragma unroll
        for (int e = 0; e < 8; ++e){
            float d2 = fmaxf(esq_n + cs[e] - 2.f * h2f(h[e]), 0.f);
            u[8*j+e] = __float_as_uint(d2);
        }
    }

    // ---- merged min(+earliest local k)/max pass ----
    unsigned vmin = u[0], vmax = u[0];
    int kmin = 0;
    #pragma unroll
    for (int k = 1; k < 64; ++k){
        if (u[k] < vmin){ vmin = u[k]; kmin = k; }
        vmax = (u[k] > vmax) ? u[k] : vmax;
    }
    // global idx of this lane's min (idx increases with k within a lane)
    unsigned im = 8u*(unsigned)lane + (unsigned)(512*(kmin >> 3) + (kmin & 7));
    #pragma unroll
    for (int o = 32; o; o >>= 1){
        unsigned v2 = (unsigned)__shfl_xor((int)vmin, o, 64);
        unsigned i2 = (unsigned)__shfl_xor((int)im,   o, 64);
        if (v2 < vmin || (v2 == vmin && i2 < im)){ vmin = v2; im = i2; }
        unsigned b2 = (unsigned)__shfl_xor((int)vmax, o, 64);
        if (b2 > vmax) vmax = b2;
    }
    unsigned umin = vmin, umax = vmax;
    int idx0 = (int)im;
    float d0 = sqrtf(__uint_as_float(umin));

    // ---- rank-99 threshold t ----
    unsigned t;
    int base = 0, bcnt = 0;
    unsigned w = 0xFFFFFFFFu;
    bool fb = false;
    if (umin == umax){
        t = umin;
    } else {
        ((uint4*)&hist[wv][0])[lane] = (uint4){0u,0u,0u,0u};
        if (lane < 2) cnts[wv][lane] = 0u;
        asm volatile("s_waitcnt lgkmcnt(0)" ::: "memory");
        float fmn = __uint_as_float(umin), fmx = __uint_as_float(umax);
        float invw = 256.0f / (fmx - fmn);
        float nb = -fmn * invw;
        unsigned bp[16];
        #pragma unroll
        for (int r = 0; r < 16; ++r) bp[r] = 0u;
        #pragma unroll
        for (int k = 0; k < 64; ++k){
            int b = (int)fmaf(__uint_as_float(u[k]), invw, nb);
            b = (b > 255) ? 255 : b;
            bp[k >> 2] |= (unsigned)b << ((k & 3) * 8);
            atomicAdd(&hist[wv][b], 1u);
        }
        asm volatile("s_waitcnt lgkmcnt(0)" ::: "memory");
        uint4 hq = ((uint4*)&hist[wv][0])[lane];
        unsigned lsum = hq.x + hq.y + hq.z + hq.w;
        unsigned inc = lsum;
        #pragma unroll
        for (int o = 1; o < 64; o <<= 1){
            unsigned y = (unsigned)__shfl_up((int)inc, o, 64);
            if (lane >= o) inc += y;
        }
        unsigned e0 = inc - lsum;
        unsigned e1 = e0 + hq.x, e2 = e1 + hq.y, e3 = e2 + hq.z, e4 = e3 + hq.w;
        int sel = -1;
        if      (e0 <= 99u && 99u < e1) sel = 0;
        else if (e1 <= 99u && 99u < e2) sel = 1;
        else if (e2 <= 99u && 99u < e3) sel = 2;
        else if (e3 <= 99u && 99u < e4) sel = 3;
        u64 bal = __ballot(sel >= 0);
        int src = __ffsll(bal) - 1;
        unsigned myBk = (unsigned)(4*lane + (sel < 0 ? 0 : sel));
        unsigned myBase = (sel == 1) ? e1 : (sel == 2) ? e2 : (sel == 3) ? e3 : e0;
        int Bk = __shfl((int)myBk,   src, 64);
        base   = __shfl((int)myBase, src, 64);
        int rk = 99 - base;
        // ---- collect: bin==Bk -> coll, bin<Bk -> coll2 (all such values < t) ----
        #pragma unroll
        for (int k = 0; k < 64; ++k){
            int b = (int)((bp[k >> 2] >> ((k & 3) * 8)) & 255u);
            if (b == Bk){
                unsigned pos = atomicAdd(&cnts[wv][0], 1u);
                if (pos < 64u) coll[wv][pos] = u[k];
            } else if (b < Bk){
                unsigned pos = atomicAdd(&cnts[wv][1], 1u);
                if (pos < 128u) coll2[wv][pos] = u[k];
            }
        }
        asm volatile("s_waitcnt lgkmcnt(0)" ::: "memory");
        bcnt = (int)cnts[wv][0];
        if (bcnt <= 64){
            w = (lane < bcnt) ? coll[wv][lane] : 0xFFFFFFFFu;
            unsigned wmn = (lane < bcnt) ? w : 0xFFFFFFFFu;
            unsigned wmx = (lane < bcnt) ? w : 0u;
            #pragma unroll
            for (int o = 32; o; o >>= 1){
                unsigned a = (unsigned)__shfl_xor((int)wmn, o, 64); if (a < wmn) wmn = a;
                unsigned b2 = (unsigned)__shfl_xor((int)wmx, o, 64); if (b2 > wmx) wmx = b2;
            }
            unsigned P;
            if (wmn == wmx) P = wmn;
            else {
                int hb = 31 - __clz((int)(wmn ^ wmx));
                unsigned mask = (hb == 31) ? 0xFFFFFFFFu : ((1u << (hb+1)) - 1u);
                P = wmn & ~mask;
                for (int b2 = hb; b2 >= 0; --b2){
                    unsigned cand = P | (1u << b2);
                    int c = __popcll(__ballot(w < cand));
                    if (c <= rk) P = cand;
                }
            }
            t = P;
        } else {
            fb = true;
            int hb = 31 - __clz((int)(umin ^ umax));
            unsigned mask = (hb == 31) ? 0xFFFFFFFFu : ((1u << (hb+1)) - 1u);
            unsigned P = umin & ~mask;
            for (int b2 = hb; b2 >= 0; --b2){
                unsigned cand = P | (1u << b2);
                int c = 0;
                #pragma unroll
                for (int k = 0; k < 64; ++k) c += (u[k] < cand) ? 1 : 0;
                #pragma unroll
                for (int o = 32; o; o >>= 1) c += __shfl_xor(c, o, 64);
                if (c <= 99) P = cand;
            }
            t = P;
        }
    }
    float tval = sqrtf(__uint_as_float(t));

    // ---- softmax denom over top-100 ----
    float s = 0.f; int cl = 0;
    if (fb){
        // rare fallback: full scan (old path)
        #pragma unroll
        for (int k = 0; k < 64; ++k){
            if (u[k] < t){ s += __expf(d0 - sqrtf(__uint_as_float(u[k]))); cl++; }
        }
        #pragma unroll
        for (int o = 32; o; o >>= 1){
            s += __shfl_xor(s, o, 64);
            cl += __shfl_xor(cl, o, 64);
        }
    } else {
        // compacted: bins<Bk (coll2, exactly 'base' values, all < t) + coll values < t
        int c_in = (int)__popcll(__ballot(w < t));
        cl = base + c_in;
        #pragma unroll
        for (int r = 0; r < 2; ++r){
            int ix = lane + 64*r;
            if (ix < base){
                float vv = __uint_as_float(coll2[wv][ix]);
                s += __expf(d0 - sqrtf(vv));
            }
        }
        if (w < t) s += __expf(d0 - sqrtf(__uint_as_float(w)));
        #pragma unroll
        for (int o = 32; o; o >>= 1) s += __shfl_xor(s, o, 64);
    }

    if (lane == 0){
        float S = s + (float)(K_ - cl) * __expf(d0 - tval);
        float dcode = sqrtf(__uint_as_float(ucode));
        if (ucode > t) S += __expf(d0 - dcode) - __expf(d0 - tval);  // include_correct swap
        float nll = dcode - d0 + __logf(S);
        pairbuf[n] = make_float2(nll, (idx0 == code) ? 1.f : 0.f);
    }
}

__global__ __launch_bounds__(1024) void finalize_kernel(const float2* __restrict__ pair,
                                                        float* __restrict__ out){
    int tid = threadIdx.x;
    float sn = 0.f, sh = 0.f;
    for (int i = tid; i < N_; i += 1024){
        float2 p = pair[i]; sn += p.x; sh += p.y;
    }
    #pragma unroll
    for (int o = 32; o; o >>= 1){ sn += __shfl_down(sn, o, 64); sh += __shfl_down(sh, o, 64); }
    __shared__ float a[16], b[16];
    int wv = tid >> 6, lane = tid & 63;
    if (lane == 0){ a[wv] = sn; b[wv] = sh; }
    __syncthreads();
    if (tid == 0){
        float L = 0.f, H = 0.f;
        #pragma unroll
        for (int i = 0; i < 16; ++i){ L += a[i]; H += b[i]; }
        out[0] = L / (float)N_;
        out[1] = H / (float)N_;   // local prediction is always candidate 0
        out[2] = H / (float)N_;
        out[3] = 1.0f;            // include_correct guarantees membership
    }
}

// ---------------- launcher ----------------
// gemm split in 2 (~41 us each) so select stays visible in rocprof top-5;
// one full-N select dispatch when the dot matrix fits the workspace.
extern "C" void kernel_launch(void* const* d_in, const int* in_sizes, int n_in,
                              void* d_out, int out_size, void* d_ws, size_t ws_size,
                              hipStream_t stream){
    const float* S   = (const float*)d_in[0];
    const int* codes = (const int*)d_in[1];
    const float* CB  = (const float*)d_in[2];
    float* out = (float*)d_out;

    char* w = (char*)d_ws;
    size_t off = 0;
    unsigned short* embT = (unsigned short*)(w + off); off += (size_t)NPAD_ * C_ * 2;
    unsigned short* CBh  = (unsigned short*)(w + off); off += (size_t)V_ * C_ * 2;
    float* csq = (float*)(w + off); off += (size_t)V_ * 4;
    float* esq = (float*)(w + off); off += (size_t)N_ * 4;
    off = (off + 255) & ~(size_t)255;
    float2* pairbuf = (float2*)(w + off); off += (size_t)N_ * 8;
    unsigned short* dotbuf = (unsigned short*)(w + off);

    size_t avail = (ws_size > off) ? ws_size - off : 0;
    long maxrows = (long)(avail / ((size_t)V_ * 2));

    hipMemsetAsync(esq, 0, (size_t)N_ * 4, stream);
    hipLaunchKernelGGL(cbconv_kernel, dim3(V_/4), dim3(256), 0, stream, CB, CBh, csq);
    hipLaunchKernelGGL(transpose_conv_kernel, dim3((T_+31)/32, C_/32, B_), dim3(32, 8), 0, stream,
                       S, embT, esq);

    if (maxrows >= N_){
        const int gchunk = 6144;   // multiple of 128
        for (int row_lo = 0; row_lo < N_; row_lo += gchunk){
            int row_hi = row_lo + gchunk; if (row_hi > N_) row_hi = N_;
            int rows = row_hi - row_lo;
            hipLaunchKernelGGL(gemm_dot_kernel, dim3((rows + 127)/128, V_/128), dim3(256), 0, stream,
                               embT, CBh, dotbuf + (size_t)row_lo * V_, row_lo, row_hi);
        }
        hipLaunchKernelGGL(select_kernel, dim3((N_ + 3)/4), dim3(256), 0, stream,
                           dotbuf, codes, esq, csq, pairbuf, 0, N_);
    } else {
        int chunk = (int)(maxrows & ~127L);
        if (chunk < 128) chunk = 128;
        for (int row_lo = 0; row_lo < N_; row_lo += chunk){
            int row_hi = row_lo + chunk; if (row_hi > N_) row_hi = N_;
            int rows = row_hi - row_lo;
            hipLaunchKernelGGL(gemm_dot_kernel, dim3((rows + 127)/128, V_/128), dim3(256), 0, stream,
                               embT, CBh, dotbuf, row_lo, row_hi);
            hipLaunchKernelGGL(select_kernel, dim3((rows + 3)/4), dim3(256), 0, stream,
                               dotbuf, codes, esq, csq, pairbuf, row_lo, rows);
        }
    }
    hipLaunchKernelGGL(finalize_kernel, dim3(1), dim3(1024), 0, stream, pairbuf, out);
}